// Round 16
// baseline (115.893 us; speedup 1.0000x reference)
//
#include <hip/hip_runtime.h>

// Chunked fast-weight linear attention, MI355X gfx950 — 3-kernel decomposition.
// K1 ttr_pt:     P_c = k_c^T v_c per (bh,chunk)            [1024 wgs, LDS-free]
// K2 ttr_prefix: W_c = exclusive prefix of P               [256 wgs]
// K3 ttr_out:    out = (mask(q k^T) v + q W_prev) / t      [2048 wgs, v-half]
// R16: K3 staging convoy shortened — v loaded as s-pairs to regs pre-B1,
// vT written as 16 ds_write_b32 (was 32 b16) POST-B1 overlapping qW+S0
// MFMAs; B1 covers k only; B2 before first Sv. Register-phased (pv dies ->
// wf dies -> S phase) to stay under the 170-reg budget at (256,3).

typedef _Float16 f16;
typedef __attribute__((ext_vector_type(2))) _Float16 f16x2;
typedef __attribute__((ext_vector_type(4))) _Float16 f16x4;
typedef __attribute__((ext_vector_type(8))) _Float16 f16x8;
typedef __attribute__((ext_vector_type(16))) float f32x16;
typedef __attribute__((ext_vector_type(4))) float fv4;
typedef __attribute__((ext_vector_type(4))) int i32x4;

#define MFMA32(a, b, c) __builtin_amdgcn_mfma_f32_32x32x16_f16((a), (b), (c), 0, 0, 0)

__device__ __forceinline__ f16x4 cvt4(fv4 x) {
  f16x2 lo = __builtin_bit_cast(f16x2, __builtin_amdgcn_cvt_pkrtz(x[0], x[1]));
  f16x2 hi = __builtin_bit_cast(f16x2, __builtin_amdgcn_cvt_pkrtz(x[2], x[3]));
  return __builtin_shufflevector(lo, hi, 0, 1, 2, 3);
}

// pack 8 f32 -> f16x8 via 4 cvt_pkrtz
__device__ __forceinline__ f16x8 pack8(const float* x) {
  i32x4 u;
#pragma unroll
  for (int t = 0; t < 4; ++t)
    u[t] = __builtin_bit_cast(
        int, __builtin_amdgcn_cvt_pkrtz(x[2 * t], x[2 * t + 1]));
  return __builtin_bit_cast(f16x8, u);
}

// Byte offset into a row-major [*][128] f16 tile (256B rows); XOR key mixes
// row bits 0-2 and 3-5 so 32-row fragment reads spread over banks.
__device__ __forceinline__ int swzb(int row, int col) {
  int s = (row ^ (row >> 3)) & 7;
  return (row << 8) + ((col << 1) ^ (s << 4));
}

// 32x32x16 operand fragment: row = lane&31, k = kk*16 + 8*(lane>>5) + j.
// Same k-map on A and B operands -> contraction correct. One ds_read_b128.
__device__ __forceinline__ f16x8 frag32(const f16* lds, int row, int kk, int lane) {
  int c0 = (kk << 4) + ((lane >> 5) << 3);
  return *(const f16x8*)((const char*)lds + swzb(row, c0));
}

// 32x32 C/D row for acc reg r, lane-half g: row=(r&3)+8*(r>>2)+4*g  [m74/m101]
__device__ __forceinline__ int rowf(int r, int g) {
  return (r & 3) + ((r >> 2) << 3) + (g << 2);
}

// ---------------------------------------------------------------------------
// K1 (R15, LDS-free): P_c^T[v][f] = sum_s v[s][v] * k[s][f]. Fragments built
// straight from global; coalesced 128B segments; L2 absorbs the re-reads.
__global__ __launch_bounds__(512, 1)
void ttr_pt(const float* __restrict__ k, const float* __restrict__ v,
            f16* __restrict__ pt) {
  const int tid = threadIdx.x, lane = tid & 63, wave = tid >> 6;
  const int l31 = lane & 31, g = lane >> 5;
  const int bh = blockIdx.x >> 5, c = blockIdx.x & 31;
  const int mt = wave >> 1, nt0 = (wave & 1) << 1;
  const float* kg = k + ((size_t)bh * 4096 + c * 128) * 128;
  const float* vg = v + ((size_t)bh * 4096 + c * 128) * 128;
  const float* va = vg + mt * 32 + l31;
  const float* kb0 = kg + nt0 * 32 + l31;
  const float* kb1 = kg + (nt0 + 1) * 32 + l31;
  f32x16 p0 = {0.f}, p1 = {0.f};
#pragma unroll
  for (int kk = 0; kk < 8; ++kk) {
    const int s0 = (kk << 4) + (g << 3);
    float a[8], b0[8], b1[8];
#pragma unroll
    for (int j = 0; j < 8; ++j) {
      a[j] = va[(s0 + j) << 7];
      b0[j] = kb0[(s0 + j) << 7];
      b1[j] = kb1[(s0 + j) << 7];
    }
    f16x8 af = pack8(a);
    p0 = MFMA32(af, pack8(b0), p0);
    p1 = MFMA32(af, pack8(b1), p1);
  }
  f16* dst = pt + (size_t)blockIdx.x * 16384;
#pragma unroll
  for (int r = 0; r < 16; ++r) {
    int vr = (mt << 5) + rowf(r, g);
    dst[vr * 128 + (nt0 << 5) + l31] = (f16)p0[r];
    dst[vr * 128 + ((nt0 + 1) << 5) + l31] = (f16)p1[r];
  }
}

// ---------------------------------------------------------------------------
// K2 (proven): exclusive prefix over chunks; B-frag-permuted output:
// per (bh,c), 16B unit u = (NT*8+kk)*64 + g*32 + laneC holds
// W[v = NT*32 + laneC][f = kk*16 + 8g .. +7]. Quarter NT is 8KB contiguous.
__global__ __launch_bounds__(256, 1)
void ttr_prefix(const f16* __restrict__ pt, f16* __restrict__ w) {
  __shared__ f16 xch[256 * 8];
  const int tid = threadIdx.x;
  const int bh = blockIdx.x >> 3, vs = blockIdx.x & 7;
  const int v0 = vs << 4;
  const int NT = v0 >> 5;
  const int vloc = tid >> 4, fblk = tid & 15;
  const size_t bhbase = (size_t)bh * 32 * 16384;
  const f16* src = pt + bhbase + (size_t)(v0 + vloc) * 128 + fblk * 8;
  const int kk = tid >> 5, gg = (tid >> 4) & 1, lc = tid & 15;
  f16* dstu = w + bhbase +
              (size_t)(((NT * 8 + kk) * 64) + gg * 32 + (v0 & 31) + lc) * 8;
  const int phi_w = vloc * 16 + (fblk ^ vloc);
  const int phi_r = lc * 16 + ((tid >> 4) ^ lc);
  float acc[8];
#pragma unroll
  for (int e = 0; e < 8; ++e) acc[e] = 0.f;
  for (int c = 0; c < 32; ++c) {
    f16x8 pcur = *(const f16x8*)(src + (size_t)c * 16384);
    f16x8 h;
#pragma unroll
    for (int e = 0; e < 8; ++e) h[e] = (f16)acc[e];
    *(f16x8*)(xch + phi_w * 8) = h;
    __syncthreads();
    f16x8 o = *(const f16x8*)(xch + phi_r * 8);
    *(f16x8*)(dstu + (size_t)c * 16384) = o;
    __syncthreads();
#pragma unroll
    for (int e = 0; e < 8; ++e) acc[e] += (float)pcur[e];
  }
}

// ---------------------------------------------------------------------------
// K3: wg = (bh, c, v-half). 4 waves; wave m owns out rows [32m,32m+32) x 64v.
// B1 covers k only; vT staged post-B1 from regs (16 b32 paired writes),
// overlapped with qW + S0 MFMAs; B2 before first Sv. 3 wg/CU.
__global__ __launch_bounds__(256, 3)
void ttr_out(const float* __restrict__ q, const float* __restrict__ k,
             const float* __restrict__ v, const f16* __restrict__ w,
             float* __restrict__ out) {
  __shared__ f16 k_lds[128 * 128];  // 32KB (read-only after B1)
  __shared__ f16 vT[64 * 128];      // 16KB: v-half transposed
  const int tid = threadIdx.x, lane = tid & 63, wave = tid >> 6;
  const int l31 = lane & 31, g = lane >> 5;
  // sibling remap: the 2 wgs sharing (bh,c) are in the same 16-window and
  // differ by 8 in blockIdx -> same XCD, concurrent -> q/k L2-hot.
  const int widx = blockIdx.x & 15;
  const int gidx = ((blockIdx.x >> 4) << 3) + (widx & 7);  // (bh,c) in [0,1024)
  const int vh = widx >> 3;                                // v-half 0..1
  const int bh = gidx >> 5, c = gidx & 31;
  const float* qg = q + ((size_t)bh * 4096 + c * 128) * 128;
  const float* kg = k + ((size_t)bh * 4096 + c * 128) * 128;
  const float* vg = v + ((size_t)bh * 4096 + c * 128) * 128 + vh * 64;

  // W B-frags (K2 layout): quarters NT = 2*vh, 2*vh+1; sibling-shared.
  const f16* wsrc = w + (size_t)gidx * 16384 + (size_t)(vh * 2) * 4096;
  f16x8 wf0[8], wf1[8];
#pragma unroll
  for (int kk = 0; kk < 8; ++kk) {
    wf0[kk] = *(const f16x8*)(wsrc + (size_t)((kk << 6) + lane) * 8);
    wf1[kk] = *(const f16x8*)(wsrc + (size_t)(4096 + ((kk << 6) + lane) * 8));
  }
  // q A/B-frags: wave-private rows, k-map = kk*16 + 8g + j (frag32 map)
  f16x8 qf[8];
  {
    const float* qr = qg + ((wave << 5) + l31) * 128 + (g << 3);
#pragma unroll
    for (int kk = 0; kk < 8; ++kk) {
      f16x4 a = cvt4(*(const fv4*)(qr + (kk << 4)));
      f16x4 b = cvt4(*(const fv4*)(qr + (kk << 4) + 4));
      qf[kk] = __builtin_shufflevector(a, b, 0, 1, 2, 3, 4, 5, 6, 7);
    }
  }
  // v s-pair loads -> regs (written to LDS post-B1). Thread: vc-group
  // g4 = tid&15 (4 cols), s-pairs a = (tid>>4) + 16p, p=0..3.
  const int g4 = tid & 15, abase = tid >> 4;
  fv4 pv0[4], pv1[4];
#pragma unroll
  for (int p = 0; p < 4; ++p) {
    int a = abase + (p << 4);
    pv0[p] = *(const fv4*)(vg + (size_t)(2 * a) * 128 + (g4 << 2));
    pv1[p] = *(const fv4*)(vg + (size_t)(2 * a + 1) * 128 + (g4 << 2));
  }
  // stage k (f32 -> f16 packed, swizzled)
  {
    const int c0 = (tid & 31) << 2;
#pragma unroll
    for (int p = 0; p < 16; ++p) {
      int s = (p << 3) + (tid >> 5);
      *(f16x4*)((char*)k_lds + swzb(s, c0)) = cvt4(*(const fv4*)(kg + s * 128 + c0));
    }
  }
  __syncthreads();  // B1: k_lds ready (pv/wf/qf loads also drained -> regs)

  // vT writes first (pv dies): 16 x ds_write_b32, pair (s,s+1) per word.
#pragma unroll
  for (int p = 0; p < 4; ++p) {
    int a = abase + (p << 4);
#pragma unroll
    for (int e = 0; e < 4; ++e) {
      int word = __builtin_bit_cast(
          int, __builtin_amdgcn_cvt_pkrtz(pv0[p][e], pv1[p][e]));
      *(int*)((char*)vT + swzb((g4 << 2) + e, 2 * a)) = word;
    }
  }
  // qW (wf dies here); o0/o1 accumulate everything from now on.
  f32x16 o0 = {0.f}, o1 = {0.f};
#pragma unroll
  for (int kk = 0; kk < 8; ++kk) {
    o0 = MFMA32(qf[kk], wf0[kk], o0);
    o1 = MFMA32(qf[kk], wf1[kk], o1);
  }
  // S tile j=0 accumulation (k_lds only) — overlaps the vT write drain.
  f32x16 sa0 = {0.f};
#pragma unroll
  for (int kk = 0; kk < 8; ++kk)
    sa0 = MFMA32(frag32(k_lds, l31, kk, lane), qf[kk], sa0);
  __syncthreads();  // B2: vT visible

  // Causal tiles j = 0..wave (S^T: lane l31 holds S[i=l31][rowf(r,g)]).
  for (int j = 0; j <= wave; ++j) {
    f32x16 sa;
    if (j == 0) {
      sa = sa0;
    } else {
      f32x16 z = {0.f};
#pragma unroll
      for (int kk = 0; kk < 8; ++kk)
        z = MFMA32(frag32(k_lds, (j << 5) + l31, kk, lane), qf[kk], z);
      sa = z;
    }
    if (j == wave) {  // diagonal: keep j_local <= i (inclusive causal)
#pragma unroll
      for (int r = 0; r < 16; ++r)
        if (rowf(r, g) > l31) sa[r] = 0.f;
    }
    // pack rows to f16 pairs: wds[t] = (j_local 2t, 2t+1) of this lane's row
    int wds[8];
#pragma unroll
    for (int t = 0; t < 8; ++t)
      wds[t] = __builtin_bit_cast(
          int, __builtin_amdgcn_cvt_pkrtz(sa[2 * t], sa[2 * t + 1]));
    // g-half exchange (lane <-> lane^32): assemble Sv A-frags
    int rA = __shfl_xor(g ? wds[0] : wds[2], 32, 64);
    int rB = __shfl_xor(g ? wds[1] : wds[3], 32, 64);
    int rC = __shfl_xor(g ? wds[4] : wds[6], 32, 64);
    int rD = __shfl_xor(g ? wds[5] : wds[7], 32, 64);
    i32x4 P0 = {g ? rA : wds[0], g ? rB : wds[1],
                g ? wds[2] : rA, g ? wds[3] : rB};
    i32x4 P1 = {g ? rC : wds[4], g ? rD : wds[5],
                g ? wds[6] : rC, g ? wds[7] : rD};
    f16x8 pa0 = __builtin_bit_cast(f16x8, P0);
    f16x8 pa1 = __builtin_bit_cast(f16x8, P1);
    // Sv: out rows i (lane) x 64 v-cols (two vT row-tiles), k-range tile j
    o0 = MFMA32(pa0, frag32(vT, l31, (j << 1), lane), o0);
    o0 = MFMA32(pa1, frag32(vT, l31, (j << 1) + 1, lane), o0);
    o1 = MFMA32(pa0, frag32(vT, 32 + l31, (j << 1), lane), o1);
    o1 = MFMA32(pa1, frag32(vT, 32 + l31, (j << 1) + 1, lane), o1);
  }

  float* og = out + (((size_t)bh * 4096) + c * 128 + (wave << 5)) * 128 + vh * 64;
#pragma unroll
  for (int r = 0; r < 16; ++r) {
    int rl = rowf(r, g);
    float tg = (float)(c * 128 + (wave << 5) + rl + 1);
    float rcp = __builtin_amdgcn_rcpf(tg);  // |rel|~1e-5 ok
    og[rl * 128 + l31] = o0[r] * rcp;
    og[rl * 128 + 32 + l31] = o1[r] * rcp;
  }
}

extern "C" void kernel_launch(void* const* d_in, const int* in_sizes, int n_in,
                              void* d_out, int out_size, void* d_ws, size_t ws_size,
                              hipStream_t stream) {
  const float* q = (const float*)d_in[0];
  const float* k = (const float*)d_in[1];
  const float* v = (const float*)d_in[2];
  float* o = (float*)d_out;
  f16* pt = (f16*)d_ws;
  f16* w = pt + (size_t)32 * 32 * 16384;
  ttr_pt<<<dim3(1024), dim3(512), 0, stream>>>(k, v, pt);
  ttr_prefix<<<dim3(256), dim3(256), 0, stream>>>(pt, w);
  ttr_out<<<dim3(2048), dim3(256), 0, stream>>>(q, k, v, w, o);
}

// Round 17
// 107.739 us; speedup vs baseline: 1.0757x; 1.0757x over previous
//
#include <hip/hip_runtime.h>

// Chunked fast-weight linear attention, MI355X gfx950 — 3-kernel decomposition.
// K1 ttr_pt:     P_c = k_c^T v_c per (bh,chunk)            [1024 wgs]
// K2 ttr_prefix: W_c = exclusive prefix of P               [256 wgs]
// K3 ttr_out:    out = (mask(q k^T) v + q W_prev) / t      [1024 wgs, 512 thr]
// R17: K3 = R11's proven per-wave schedule, but the two v-half siblings are
// merged into one 512-thread wg: k staged ONCE per (bh,c) (halves k fetch +
// staging issue), LDS 64KB -> 2 wg/CU = 16 waves/CU (was 12). Single
// barrier, register plan unchanged (84 measured < 128 cap at (512,4)).
// K1/K2 byte-identical to R11.

typedef _Float16 f16;
typedef __attribute__((ext_vector_type(2))) _Float16 f16x2;
typedef __attribute__((ext_vector_type(4))) _Float16 f16x4;
typedef __attribute__((ext_vector_type(8))) _Float16 f16x8;
typedef __attribute__((ext_vector_type(16))) float f32x16;
typedef __attribute__((ext_vector_type(4))) float fv4;
typedef __attribute__((ext_vector_type(4))) int i32x4;

#define MFMA32(a, b, c) __builtin_amdgcn_mfma_f32_32x32x16_f16((a), (b), (c), 0, 0, 0)

__device__ __forceinline__ f16x4 cvt4(fv4 x) {
  f16x2 lo = __builtin_bit_cast(f16x2, __builtin_amdgcn_cvt_pkrtz(x[0], x[1]));
  f16x2 hi = __builtin_bit_cast(f16x2, __builtin_amdgcn_cvt_pkrtz(x[2], x[3]));
  return __builtin_shufflevector(lo, hi, 0, 1, 2, 3);
}

// Byte offset into a row-major [*][128] f16 tile (256B rows); XOR key mixes
// row bits 0-2 and 3-5 so 32-row fragment reads spread over banks.
__device__ __forceinline__ int swzb(int row, int col) {
  int s = (row ^ (row >> 3)) & 7;
  return (row << 8) + ((col << 1) ^ (s << 4));
}

// 32x32x16 operand fragment: row = lane&31, k = kk*16 + 8*(lane>>5) + j.
// Same k-map on A and B operands -> contraction correct. One ds_read_b128.
__device__ __forceinline__ f16x8 frag32(const f16* lds, int row, int kk, int lane) {
  int c0 = (kk << 4) + ((lane >> 5) << 3);
  return *(const f16x8*)((const char*)lds + swzb(row, c0));
}

// 32x32 C/D row for acc reg r, lane-half g: row=(r&3)+8*(r>>2)+4*g  [m74/m101]
__device__ __forceinline__ int rowf(int r, int g) {
  return (r & 3) + ((r >> 2) << 3) + (g << 2);
}

// ---------------------------------------------------------------------------
// K1 (R11, proven): P_c^T[v][f] = sum_s v[s][v] * k[s][f]
__global__ __launch_bounds__(512, 1)
void ttr_pt(const float* __restrict__ k, const float* __restrict__ v,
            f16* __restrict__ pt) {
  __shared__ f16 kT[128 * 128];
  __shared__ f16 vT[128 * 128];
  const int tid = threadIdx.x, lane = tid & 63, wave = tid >> 6;
  const int bh = blockIdx.x >> 5, c = blockIdx.x & 31;
  const float* kg = k + ((size_t)bh * 4096 + c * 128) * 128;
  const float* vg = v + ((size_t)bh * 4096 + c * 128) * 128;
  const int f0 = (tid & 31) << 2;
#pragma unroll
  for (int p = 0; p < 8; ++p) {
    int s = (p << 4) + (tid >> 5);
    fv4 xk = *(const fv4*)(kg + s * 128 + f0);
    fv4 xv = *(const fv4*)(vg + s * 128 + f0);
#pragma unroll
    for (int e = 0; e < 4; ++e) {
      *(f16*)((char*)kT + swzb(f0 + e, s)) = (f16)xk[e];
      *(f16*)((char*)vT + swzb(f0 + e, s)) = (f16)xv[e];
    }
  }
  __syncthreads();
  const int l31 = lane & 31, g = lane >> 5;
  const int mt = wave >> 1, nt0 = (wave & 1) << 1;
  f32x16 p0 = {0.f}, p1 = {0.f};
#pragma unroll
  for (int kk = 0; kk < 8; ++kk) {
    f16x8 a = frag32(vT, (mt << 5) + l31, kk, lane);
    p0 = MFMA32(a, frag32(kT, (nt0 << 5) + l31, kk, lane), p0);
    p1 = MFMA32(a, frag32(kT, ((nt0 + 1) << 5) + l31, kk, lane), p1);
  }
  f16* dst = pt + (size_t)blockIdx.x * 16384;
#pragma unroll
  for (int r = 0; r < 16; ++r) {
    int vr = (mt << 5) + rowf(r, g);
    dst[vr * 128 + (nt0 << 5) + l31] = (f16)p0[r];
    dst[vr * 128 + ((nt0 + 1) << 5) + l31] = (f16)p1[r];
  }
}

// ---------------------------------------------------------------------------
// K2 (proven): exclusive prefix over chunks; B-frag-permuted output:
// per (bh,c), 16B unit u = (NT*8+kk)*64 + g*32 + laneC holds
// W[v = NT*32 + laneC][f = kk*16 + 8g .. +7]. Quarter NT is 8KB contiguous.
__global__ __launch_bounds__(256, 1)
void ttr_prefix(const f16* __restrict__ pt, f16* __restrict__ w) {
  __shared__ f16 xch[256 * 8];
  const int tid = threadIdx.x;
  const int bh = blockIdx.x >> 3, vs = blockIdx.x & 7;
  const int v0 = vs << 4;
  const int NT = v0 >> 5;
  const int vloc = tid >> 4, fblk = tid & 15;
  const size_t bhbase = (size_t)bh * 32 * 16384;
  const f16* src = pt + bhbase + (size_t)(v0 + vloc) * 128 + fblk * 8;
  const int kk = tid >> 5, gg = (tid >> 4) & 1, lc = tid & 15;
  f16* dstu = w + bhbase +
              (size_t)(((NT * 8 + kk) * 64) + gg * 32 + (v0 & 31) + lc) * 8;
  const int phi_w = vloc * 16 + (fblk ^ vloc);
  const int phi_r = lc * 16 + ((tid >> 4) ^ lc);
  float acc[8];
#pragma unroll
  for (int e = 0; e < 8; ++e) acc[e] = 0.f;
  for (int c = 0; c < 32; ++c) {
    f16x8 pcur = *(const f16x8*)(src + (size_t)c * 16384);
    f16x8 h;
#pragma unroll
    for (int e = 0; e < 8; ++e) h[e] = (f16)acc[e];
    *(f16x8*)(xch + phi_w * 8) = h;
    __syncthreads();
    f16x8 o = *(const f16x8*)(xch + phi_r * 8);
    *(f16x8*)(dstu + (size_t)c * 16384) = o;
    __syncthreads();
#pragma unroll
    for (int e = 0; e < 8; ++e) acc[e] += (float)pcur[e];
  }
}

// ---------------------------------------------------------------------------
// K3: wg = (bh, c), 512 threads / 8 waves. Wave w -> (m = w&3, vh = w>>2):
// out rows [32m,32m+32) x v-cols [64vh, 64vh+64). k staged once; single
// barrier; S^T in regs + cvt_pk/shfl transpose (R11 schedule per wave).
__global__ __launch_bounds__(512, 4)
void ttr_out(const float* __restrict__ q, const float* __restrict__ k,
             const float* __restrict__ v, const f16* __restrict__ w,
             float* __restrict__ out) {
  __shared__ f16 k_lds[128 * 128];  // 32KB (read-only after B1)
  __shared__ f16 vT[128 * 128];     // 32KB: all 128 v-cols transposed
  const int tid = threadIdx.x, lane = tid & 63, w8 = tid >> 6;  // 0..7
  const int m = w8 & 3, vh = w8 >> 2;
  const int l31 = lane & 31, g = lane >> 5;
  const int gidx = blockIdx.x;  // (bh,c) in [0,1024)
  const int bh = gidx >> 5, c = gidx & 31;
  const float* qg = q + ((size_t)bh * 4096 + c * 128) * 128;
  const float* kg = k + ((size_t)bh * 4096 + c * 128) * 128;
  const float* vg = v + ((size_t)bh * 4096 + c * 128) * 128;

  // W B-frags (K2 layout): quarters NT = 2vh, 2vh+1 (8KB each).
  const f16* wsrc = w + (size_t)gidx * 16384 + (size_t)(vh * 2) * 4096;
  f16x8 wf0[8], wf1[8];
#pragma unroll
  for (int kk = 0; kk < 8; ++kk) {
    wf0[kk] = *(const f16x8*)(wsrc + (size_t)((kk << 6) + lane) * 8);
    wf1[kk] = *(const f16x8*)(wsrc + (size_t)(4096 + ((kk << 6) + lane) * 8));
  }
  // q A/B-frags: wave-private rows (m*32+l31); waves m and m+4 share -> L1.
  f16x8 qf[8];
  {
    const float* qr = qg + ((m << 5) + l31) * 128 + (g << 3);
#pragma unroll
    for (int kk = 0; kk < 8; ++kk) {
      f16x4 a = cvt4(*(const fv4*)(qr + (kk << 4)));
      f16x4 b = cvt4(*(const fv4*)(qr + (kk << 4) + 4));
      qf[kk] = __builtin_shufflevector(a, b, 0, 1, 2, 3, 4, 5, 6, 7);
    }
  }
  // stage k ONCE (512 threads: 8 fv4 each; f32 -> f16 packed, swizzled)
  {
    const int c0 = (tid & 31) << 2;
#pragma unroll
    for (int p = 0; p < 8; ++p) {
      int s = (p << 4) + (tid >> 5);
      *(f16x4*)((char*)k_lds + swzb(s, c0)) = cvt4(*(const fv4*)(kg + s * 128 + c0));
    }
  }
  // stage vT, all 128 cols (transposed scalar writes; 8 fv4 each)
  {
    const int c0 = (tid & 31) << 2;
#pragma unroll
    for (int p = 0; p < 8; ++p) {
      int s = (p << 4) + (tid >> 5);
      fv4 xv = *(const fv4*)(vg + s * 128 + c0);
#pragma unroll
      for (int e = 0; e < 4; ++e)
        *(f16*)((char*)vT + swzb(c0 + e, s)) = (f16)xv[e];
    }
  }
  __syncthreads();  // B1 — the ONLY barrier

  // qW first: wf0/wf1 die here; o0/o1 accumulate everything from now on.
  f32x16 o0 = {0.f}, o1 = {0.f};
#pragma unroll
  for (int kk = 0; kk < 8; ++kk) {
    o0 = MFMA32(qf[kk], wf0[kk], o0);
    o1 = MFMA32(qf[kk], wf1[kk], o1);
  }

  // Causal tiles j = 0..m. S^T = MFMA(A=k block j, B=qf):
  // lane l31 holds S[i=l31][j_local = rowf(r,g)] — one acc tile live.
  for (int j = 0; j <= m; ++j) {
    f32x16 sa = {0.f};
#pragma unroll
    for (int kk = 0; kk < 8; ++kk)
      sa = MFMA32(frag32(k_lds, (j << 5) + l31, kk, lane), qf[kk], sa);
    if (j == m) {  // diagonal: keep j_local <= i (inclusive causal)
#pragma unroll
      for (int r = 0; r < 16; ++r)
        if (rowf(r, g) > l31) sa[r] = 0.f;
    }
    // pack rows to f16 pairs: wds[t] = (j_local 2t, 2t+1) of this lane's row
    int wds[8];
#pragma unroll
    for (int t = 0; t < 8; ++t)
      wds[t] = __builtin_bit_cast(
          int, __builtin_amdgcn_cvt_pkrtz(sa[2 * t], sa[2 * t + 1]));
    // g-half exchange (lane <-> lane^32): assemble Sv A-frags
    int rA = __shfl_xor(g ? wds[0] : wds[2], 32, 64);
    int rB = __shfl_xor(g ? wds[1] : wds[3], 32, 64);
    int rC = __shfl_xor(g ? wds[4] : wds[6], 32, 64);
    int rD = __shfl_xor(g ? wds[5] : wds[7], 32, 64);
    i32x4 P0 = {g ? rA : wds[0], g ? rB : wds[1],
                g ? wds[2] : rA, g ? wds[3] : rB};
    i32x4 P1 = {g ? rC : wds[4], g ? rD : wds[5],
                g ? wds[6] : rC, g ? wds[7] : rD};
    f16x8 pa0 = __builtin_bit_cast(f16x8, P0);
    f16x8 pa1 = __builtin_bit_cast(f16x8, P1);
    // Sv: out rows i (lane) x this wave's 64 v-cols, k-range of tile j
    o0 = MFMA32(pa0, frag32(vT, (vh << 6) + l31, (j << 1), lane), o0);
    o0 = MFMA32(pa1, frag32(vT, (vh << 6) + l31, (j << 1) + 1, lane), o0);
    o1 = MFMA32(pa0, frag32(vT, (vh << 6) + 32 + l31, (j << 1), lane), o1);
    o1 = MFMA32(pa1, frag32(vT, (vh << 6) + 32 + l31, (j << 1) + 1, lane), o1);
  }

  float* og = out + (((size_t)bh * 4096) + c * 128 + (m << 5)) * 128 + vh * 64;
#pragma unroll
  for (int r = 0; r < 16; ++r) {
    int rl = rowf(r, g);
    float tg = (float)(c * 128 + (m << 5) + rl + 1);
    float rcp = __builtin_amdgcn_rcpf(tg);  // |rel|~1e-5 ok
    og[rl * 128 + l31] = o0[r] * rcp;
    og[rl * 128 + 32 + l31] = o1[r] * rcp;
  }
}

extern "C" void kernel_launch(void* const* d_in, const int* in_sizes, int n_in,
                              void* d_out, int out_size, void* d_ws, size_t ws_size,
                              hipStream_t stream) {
  const float* q = (const float*)d_in[0];
  const float* k = (const float*)d_in[1];
  const float* v = (const float*)d_in[2];
  float* o = (float*)d_out;
  f16* pt = (f16*)d_ws;
  f16* w = pt + (size_t)32 * 32 * 16384;
  ttr_pt<<<dim3(1024), dim3(512), 0, stream>>>(k, v, pt);
  ttr_prefix<<<dim3(256), dim3(256), 0, stream>>>(pt, w);
  ttr_out<<<dim3(1024), dim3(512), 0, stream>>>(q, k, v, w, o);
}

// Round 18
// 95.252 us; speedup vs baseline: 1.2167x; 1.1311x over previous
//
#include <hip/hip_runtime.h>

// Chunked fast-weight linear attention, MI355X gfx950 — 3-kernel decomposition.
// K1 ttr_pt:     P_c = k_c^T v_c per (bh,chunk)            [1024 wgs]
// K2 ttr_prefix: W_c = exclusive prefix of P               [256 wgs]
// K3 ttr_out:    out = (mask(q k^T) v + q W_prev) / t      [2048 wgs, v-half]
// R18: lock-in of the verified optimum (R11, 96.07us) + K2 double-buffered
// exchange (barriers 64->32). R12-R17 established: K3's schedule needs the
// 170-reg budget at (256,3); every <=128-reg config spills (R7/R8/R17);
// density lever saturates at v-half (R12); producer handoffs and manual
// pipelining regress (R13/R16/R2). K1/K2 at BW floor.

typedef _Float16 f16;
typedef __attribute__((ext_vector_type(2))) _Float16 f16x2;
typedef __attribute__((ext_vector_type(4))) _Float16 f16x4;
typedef __attribute__((ext_vector_type(8))) _Float16 f16x8;
typedef __attribute__((ext_vector_type(16))) float f32x16;
typedef __attribute__((ext_vector_type(4))) float fv4;
typedef __attribute__((ext_vector_type(4))) int i32x4;

#define MFMA32(a, b, c) __builtin_amdgcn_mfma_f32_32x32x16_f16((a), (b), (c), 0, 0, 0)

__device__ __forceinline__ f16x4 cvt4(fv4 x) {
  f16x2 lo = __builtin_bit_cast(f16x2, __builtin_amdgcn_cvt_pkrtz(x[0], x[1]));
  f16x2 hi = __builtin_bit_cast(f16x2, __builtin_amdgcn_cvt_pkrtz(x[2], x[3]));
  return __builtin_shufflevector(lo, hi, 0, 1, 2, 3);
}

// Byte offset into a row-major [*][128] f16 tile (256B rows); XOR key mixes
// row bits 0-2 and 3-5 so 32-row fragment reads spread over banks.
__device__ __forceinline__ int swzb(int row, int col) {
  int s = (row ^ (row >> 3)) & 7;
  return (row << 8) + ((col << 1) ^ (s << 4));
}

// 32x32x16 operand fragment: row = lane&31, k = kk*16 + 8*(lane>>5) + j.
// Same k-map on A and B operands -> contraction correct. One ds_read_b128.
__device__ __forceinline__ f16x8 frag32(const f16* lds, int row, int kk, int lane) {
  int c0 = (kk << 4) + ((lane >> 5) << 3);
  return *(const f16x8*)((const char*)lds + swzb(row, c0));
}

// 32x32 C/D row for acc reg r, lane-half g: row=(r&3)+8*(r>>2)+4*g  [m74/m101]
__device__ __forceinline__ int rowf(int r, int g) {
  return (r & 3) + ((r >> 2) << 3) + (g << 2);
}

// ---------------------------------------------------------------------------
// K1 (R11, proven): P_c^T[v][f] = sum_s v[s][v] * k[s][f]
__global__ __launch_bounds__(512, 1)
void ttr_pt(const float* __restrict__ k, const float* __restrict__ v,
            f16* __restrict__ pt) {
  __shared__ f16 kT[128 * 128];
  __shared__ f16 vT[128 * 128];
  const int tid = threadIdx.x, lane = tid & 63, wave = tid >> 6;
  const int bh = blockIdx.x >> 5, c = blockIdx.x & 31;
  const float* kg = k + ((size_t)bh * 4096 + c * 128) * 128;
  const float* vg = v + ((size_t)bh * 4096 + c * 128) * 128;
  const int f0 = (tid & 31) << 2;
#pragma unroll
  for (int p = 0; p < 8; ++p) {
    int s = (p << 4) + (tid >> 5);
    fv4 xk = *(const fv4*)(kg + s * 128 + f0);
    fv4 xv = *(const fv4*)(vg + s * 128 + f0);
#pragma unroll
    for (int e = 0; e < 4; ++e) {
      *(f16*)((char*)kT + swzb(f0 + e, s)) = (f16)xk[e];
      *(f16*)((char*)vT + swzb(f0 + e, s)) = (f16)xv[e];
    }
  }
  __syncthreads();
  const int l31 = lane & 31, g = lane >> 5;
  const int mt = wave >> 1, nt0 = (wave & 1) << 1;
  f32x16 p0 = {0.f}, p1 = {0.f};
#pragma unroll
  for (int kk = 0; kk < 8; ++kk) {
    f16x8 a = frag32(vT, (mt << 5) + l31, kk, lane);
    p0 = MFMA32(a, frag32(kT, (nt0 << 5) + l31, kk, lane), p0);
    p1 = MFMA32(a, frag32(kT, ((nt0 + 1) << 5) + l31, kk, lane), p1);
  }
  f16* dst = pt + (size_t)blockIdx.x * 16384;
#pragma unroll
  for (int r = 0; r < 16; ++r) {
    int vr = (mt << 5) + rowf(r, g);
    dst[vr * 128 + (nt0 << 5) + l31] = (f16)p0[r];
    dst[vr * 128 + ((nt0 + 1) << 5) + l31] = (f16)p1[r];
  }
}

// ---------------------------------------------------------------------------
// K2: exclusive prefix over chunks; B-frag-permuted output:
// per (bh,c), 16B unit u = (NT*8+kk)*64 + g*32 + laneC holds
// W[v = NT*32 + laneC][f = kk*16 + 8g .. +7]. Quarter NT is 8KB contiguous.
// R18: double-buffered exchange -> ONE barrier per chunk (was two).
__global__ __launch_bounds__(256, 1)
void ttr_prefix(const f16* __restrict__ pt, f16* __restrict__ w) {
  __shared__ f16 xch[2][256 * 8];
  const int tid = threadIdx.x;
  const int bh = blockIdx.x >> 3, vs = blockIdx.x & 7;
  const int v0 = vs << 4;
  const int NT = v0 >> 5;
  const int vloc = tid >> 4, fblk = tid & 15;
  const size_t bhbase = (size_t)bh * 32 * 16384;
  const f16* src = pt + bhbase + (size_t)(v0 + vloc) * 128 + fblk * 8;
  const int kk = tid >> 5, gg = (tid >> 4) & 1, lc = tid & 15;
  f16* dstu = w + bhbase +
              (size_t)(((NT * 8 + kk) * 64) + gg * 32 + (v0 & 31) + lc) * 8;
  const int phi_w = vloc * 16 + (fblk ^ vloc);
  const int phi_r = lc * 16 + ((tid >> 4) ^ lc);
  float acc[8];
#pragma unroll
  for (int e = 0; e < 8; ++e) acc[e] = 0.f;
  for (int c = 0; c < 32; ++c) {
    f16x8 pcur = *(const f16x8*)(src + (size_t)c * 16384);  // issue early
    f16x8 h;
#pragma unroll
    for (int e = 0; e < 8; ++e) h[e] = (f16)acc[e];
    f16* buf = xch[c & 1];
    *(f16x8*)(buf + phi_w * 8) = h;
    __syncthreads();  // this buffer's writes visible; other buffer untouched
    f16x8 o = *(const f16x8*)(buf + phi_r * 8);
    *(f16x8*)(dstu + (size_t)c * 16384) = o;  // exclusive prefix (W[0]=0)
#pragma unroll
    for (int e = 0; e < 8; ++e) acc[e] += (float)pcur[e];
  }
}

// ---------------------------------------------------------------------------
// K3 (R11, proven): wg = (bh, c, v-half). 4 waves; wave m owns out rows
// [32m,32m+32) x 64 v. Single barrier; S^T + in-reg transpose; 3 wg/CU.
__global__ __launch_bounds__(256, 3)
void ttr_out(const float* __restrict__ q, const float* __restrict__ k,
             const float* __restrict__ v, const f16* __restrict__ w,
             float* __restrict__ out) {
  __shared__ f16 k_lds[128 * 128];  // 32KB (read-only after B1)
  __shared__ f16 vT[64 * 128];      // 16KB: v-half transposed
  const int tid = threadIdx.x, lane = tid & 63, wave = tid >> 6;
  const int l31 = lane & 31, g = lane >> 5;
  // sibling remap: the 2 wgs sharing (bh,c) are in the same 16-window and
  // differ by 8 in blockIdx -> same XCD, concurrent -> q/k L2-hot.
  const int widx = blockIdx.x & 15;
  const int gidx = ((blockIdx.x >> 4) << 3) + (widx & 7);  // (bh,c) in [0,1024)
  const int vh = widx >> 3;                                // v-half 0..1
  const int bh = gidx >> 5, c = gidx & 31;
  const float* qg = q + ((size_t)bh * 4096 + c * 128) * 128;
  const float* kg = k + ((size_t)bh * 4096 + c * 128) * 128;
  const float* vg = v + ((size_t)bh * 4096 + c * 128) * 128 + vh * 64;

  // W B-frags (K2 layout): quarters NT = 2*vh, 2*vh+1; sibling-shared.
  const f16* wsrc = w + (size_t)gidx * 16384 + (size_t)(vh * 2) * 4096;
  f16x8 wf0[8], wf1[8];
#pragma unroll
  for (int kk = 0; kk < 8; ++kk) {
    wf0[kk] = *(const f16x8*)(wsrc + (size_t)((kk << 6) + lane) * 8);
    wf1[kk] = *(const f16x8*)(wsrc + (size_t)(4096 + ((kk << 6) + lane) * 8));
  }
  // q A/B-frags: wave-private rows, k-map = kk*16 + 8g + j (frag32 map)
  f16x8 qf[8];
  {
    const float* qr = qg + ((wave << 5) + l31) * 128 + (g << 3);
#pragma unroll
    for (int kk = 0; kk < 8; ++kk) {
      f16x4 a = cvt4(*(const fv4*)(qr + (kk << 4)));
      f16x4 b = cvt4(*(const fv4*)(qr + (kk << 4) + 4));
      qf[kk] = __builtin_shufflevector(a, b, 0, 1, 2, 3, 4, 5, 6, 7);
    }
  }
  // stage k (f32 -> f16 packed, swizzled)
  {
    const int c0 = (tid & 31) << 2;
#pragma unroll
    for (int p = 0; p < 16; ++p) {
      int s = (p << 3) + (tid >> 5);
      *(f16x4*)((char*)k_lds + swzb(s, c0)) = cvt4(*(const fv4*)(kg + s * 128 + c0));
    }
  }
  // stage vT (v-half transposed; vT row = local v-col 0..63, col = s)
  {
    const int c0 = (tid & 15) << 2;
#pragma unroll
    for (int p = 0; p < 8; ++p) {
      int s = (p << 4) + (tid >> 4);
      fv4 xv = *(const fv4*)(vg + s * 128 + c0);
#pragma unroll
      for (int e = 0; e < 4; ++e)
        *(f16*)((char*)vT + swzb(c0 + e, s)) = (f16)xv[e];
    }
  }
  __syncthreads();  // B1 — the ONLY barrier

  // qW first: wf0/wf1 die here; o0/o1 accumulate everything from now on.
  f32x16 o0 = {0.f}, o1 = {0.f};
#pragma unroll
  for (int kk = 0; kk < 8; ++kk) {
    o0 = MFMA32(qf[kk], wf0[kk], o0);
    o1 = MFMA32(qf[kk], wf1[kk], o1);
  }

  // Causal tiles j = 0..wave. S^T = MFMA(A=k block j, B=qf):
  // lane l31 holds S[i=l31][j_local = rowf(r,g)] — one acc tile live.
  for (int j = 0; j <= wave; ++j) {
    f32x16 sa = {0.f};
#pragma unroll
    for (int kk = 0; kk < 8; ++kk)
      sa = MFMA32(frag32(k_lds, (j << 5) + l31, kk, lane), qf[kk], sa);
    if (j == wave) {  // diagonal: keep j_local <= i (inclusive causal)
#pragma unroll
      for (int r = 0; r < 16; ++r)
        if (rowf(r, g) > l31) sa[r] = 0.f;
    }
    // pack rows to f16 pairs: wds[t] = (j_local 2t, 2t+1) of this lane's row
    int wds[8];
#pragma unroll
    for (int t = 0; t < 8; ++t)
      wds[t] = __builtin_bit_cast(
          int, __builtin_amdgcn_cvt_pkrtz(sa[2 * t], sa[2 * t + 1]));
    // g-half exchange (lane <-> lane^32): assemble Sv A-frags
    int rA = __shfl_xor(g ? wds[0] : wds[2], 32, 64);
    int rB = __shfl_xor(g ? wds[1] : wds[3], 32, 64);
    int rC = __shfl_xor(g ? wds[4] : wds[6], 32, 64);
    int rD = __shfl_xor(g ? wds[5] : wds[7], 32, 64);
    i32x4 P0 = {g ? rA : wds[0], g ? rB : wds[1],
                g ? wds[2] : rA, g ? wds[3] : rB};
    i32x4 P1 = {g ? rC : wds[4], g ? rD : wds[5],
                g ? wds[6] : rC, g ? wds[7] : rD};
    f16x8 pa0 = __builtin_bit_cast(f16x8, P0);
    f16x8 pa1 = __builtin_bit_cast(f16x8, P1);
    // Sv: out rows i (lane) x 64 v-cols (two vT row-tiles), k-range tile j
    o0 = MFMA32(pa0, frag32(vT, l31, (j << 1), lane), o0);
    o0 = MFMA32(pa1, frag32(vT, l31, (j << 1) + 1, lane), o0);
    o1 = MFMA32(pa0, frag32(vT, 32 + l31, (j << 1), lane), o1);
    o1 = MFMA32(pa1, frag32(vT, 32 + l31, (j << 1) + 1, lane), o1);
  }

  float* og = out + (((size_t)bh * 4096) + c * 128 + (wave << 5)) * 128 + vh * 64;
#pragma unroll
  for (int r = 0; r < 16; ++r) {
    int rl = rowf(r, g);
    float tg = (float)(c * 128 + (wave << 5) + rl + 1);
    float rcp = __builtin_amdgcn_rcpf(tg);  // |rel|~1e-5 ok
    og[rl * 128 + l31] = o0[r] * rcp;
    og[rl * 128 + 32 + l31] = o1[r] * rcp;
  }
}

extern "C" void kernel_launch(void* const* d_in, const int* in_sizes, int n_in,
                              void* d_out, int out_size, void* d_ws, size_t ws_size,
                              hipStream_t stream) {
  const float* q = (const float*)d_in[0];
  const float* k = (const float*)d_in[1];
  const float* v = (const float*)d_in[2];
  float* o = (float*)d_out;
  f16* pt = (f16*)d_ws;
  f16* w = pt + (size_t)32 * 32 * 16384;
  ttr_pt<<<dim3(1024), dim3(512), 0, stream>>>(k, v, pt);
  ttr_prefix<<<dim3(256), dim3(256), 0, stream>>>(pt, w);
  ttr_out<<<dim3(2048), dim3(256), 0, stream>>>(q, k, v, w, o);
}